// Round 2
// baseline (37.007 us; speedup 1.0000x reference)
//
#include <hip/hip_runtime.h>

// Pesudo_RenderNet — per-camera frustum raycast into a semantic voxel grid;
// outputs first non-ignore class + its depth per pixel.
// Outputs (concat float32): sem_view (1,5,64,176), depth_map (1,5,64,176).
//
// Numerics: replicate numpy's fp32 chain exactly.
//  - np.linalg.inv == LAPACK sgesv (getf2 LU w/ partial pivoting + getrs),
//    multipliers via reciprocal-scal, backsolve via reciprocal-diag multiply
//    (OpenBLAS trsm semantics).
//  - np.einsum (optimize=False) == sequential j=0,1,2 mul+add fp32, no FMA.

#define IMG_H 64
#define IMG_W 176
#define NCAM  5
#define NDEPTH 88
#define XDIM 200
#define YDIM 200
#define ZDIM 16
#define NCLS 10
#define IGN  9

__device__ __forceinline__ float dot3(const float r[3], float v0, float v1, float v2) {
    // sequential j=0,1,2 accumulation, round each op, no FMA (numpy einsum)
    return __fadd_rn(__fadd_rn(__fmul_rn(r[0], v0), __fmul_rn(r[1], v1)),
                     __fmul_rn(r[2], v2));
}

// 3x3 inverse replicating LAPACK sgesv in fp32 (numpy np.linalg.inv path):
// sgetf2 (partial pivot, first-max; multipliers = a * (1/pivot)),
// sger trailing update (mul+add), then getrs: unit-lower forward solve,
// upper backsolve multiplying by precomputed reciprocal diagonals.
__device__ void inv3x3_gesv(const float* __restrict__ m, float out[3][3]) {
    float a[3][3];
    #pragma unroll
    for (int r = 0; r < 3; ++r)
        #pragma unroll
        for (int c = 0; c < 3; ++c)
            a[r][c] = m[r * 3 + c];

    int piv0, piv1;
    // ---- getf2: column 0 ----
    {
        int p = 0; float mx = fabsf(a[0][0]);
        if (fabsf(a[1][0]) > mx) { mx = fabsf(a[1][0]); p = 1; }
        if (fabsf(a[2][0]) > mx) { p = 2; }
        piv0 = p;
        if (p != 0) {
            #pragma unroll
            for (int c = 0; c < 3; ++c) { float t = a[0][c]; a[0][c] = a[p][c]; a[p][c] = t; }
        }
        float r0 = __fdiv_rn(1.0f, a[0][0]);
        a[1][0] = __fmul_rn(a[1][0], r0);
        a[2][0] = __fmul_rn(a[2][0], r0);
        #pragma unroll
        for (int j = 1; j < 3; ++j) {      // sger, alpha = -1: temp = -a0j
            float t = -a[0][j];
            a[1][j] = __fadd_rn(a[1][j], __fmul_rn(a[1][0], t));
            a[2][j] = __fadd_rn(a[2][j], __fmul_rn(a[2][0], t));
        }
    }
    // ---- getf2: column 1 ----
    {
        int p = 1; float mx = fabsf(a[1][1]);
        if (fabsf(a[2][1]) > mx) { p = 2; }
        piv1 = p;
        if (p != 1) {
            #pragma unroll
            for (int c = 0; c < 3; ++c) { float t = a[1][c]; a[1][c] = a[2][c]; a[2][c] = t; }
        }
        float r1 = __fdiv_rn(1.0f, a[1][1]);
        a[2][1] = __fmul_rn(a[2][1], r1);
        a[2][2] = __fadd_rn(a[2][2], __fmul_rn(a[2][1], -a[1][2]));
    }

    // reciprocal diagonals (OpenBLAS trsm packs inverted diag entries)
    float iu0 = __fdiv_rn(1.0f, a[0][0]);
    float iu1 = __fdiv_rn(1.0f, a[1][1]);
    float iu2 = __fdiv_rn(1.0f, a[2][2]);

    // ---- getrs: B = I, column by column ----
    #pragma unroll
    for (int k = 0; k < 3; ++k) {
        float b[3] = {0.0f, 0.0f, 0.0f};
        b[k] = 1.0f;
        // slaswp row interchanges (sequential)
        { float t = b[0]; b[0] = b[piv0]; b[piv0] = t; }
        { float t = b[1]; b[1] = b[piv1]; b[piv1] = t; }
        // forward solve, unit lower: b_i -= b_k * l_ik
        b[1] = __fsub_rn(b[1], __fmul_rn(b[0], a[1][0]));
        b[2] = __fsub_rn(b[2], __fmul_rn(b[0], a[2][0]));
        b[2] = __fsub_rn(b[2], __fmul_rn(b[1], a[2][1]));
        // back solve, non-unit upper, reciprocal-diag multiply
        b[2] = __fmul_rn(b[2], iu2);
        b[1] = __fsub_rn(b[1], __fmul_rn(b[2], a[1][2]));
        b[0] = __fsub_rn(b[0], __fmul_rn(b[2], a[0][2]));
        b[1] = __fmul_rn(b[1], iu1);
        b[0] = __fsub_rn(b[0], __fmul_rn(b[1], a[0][1]));
        b[0] = __fmul_rn(b[0], iu0);
        out[0][k] = b[0];
        out[1][k] = b[1];
        out[2][k] = b[2];
    }
}

__global__ __launch_bounds__(256)
void Pesudo_RenderNet_kernel(const float* __restrict__ c2e_rot,
                             const float* __restrict__ c2e_trans,
                             const float* __restrict__ cam2img,
                             const float* __restrict__ post_rots,
                             const float* __restrict__ post_trans,
                             const float* __restrict__ sem_map,
                             float* __restrict__ out) {
    const int PPC = IMG_H * IMG_W;
    int t = blockIdx.x * blockDim.x + threadIdx.x;
    if (t >= NCAM * PPC) return;
    int n   = t / PPC;
    int rem = t - n * PPC;
    int h   = rem / IMG_W;
    int w   = rem - h * IMG_W;

    float iPR[3][3], iK[3][3], R[3][3];
    inv3x3_gesv(post_rots + n * 9, iPR);
    inv3x3_gesv(cam2img  + n * 9, iK);
    #pragma unroll
    for (int i = 0; i < 3; ++i)
        #pragma unroll
        for (int j = 0; j < 3; ++j)
            R[i][j] = c2e_rot[n * 9 + i * 3 + j];
    float tx  = c2e_trans[n * 3 + 0], ty  = c2e_trans[n * 3 + 1], tz  = c2e_trans[n * 3 + 2];
    float tp0 = post_trans[n * 3 + 0], tp1 = post_trans[n * 3 + 1], tp2 = post_trans[n * 3 + 2];

    // frustum pixel coords (x = w+0.5, y = h+0.5), scaled by DS=4
    float x = (float)w + 0.5f;
    float y = (float)h + 0.5f;
    // step 1: pix*ds - post_trans
    float v0 = __fsub_rn(__fmul_rn(4.0f, x), tp0);
    float v1 = __fsub_rn(__fmul_rn(4.0f, y), tp1);
    float v2 = __fsub_rn(1.0f, tp2);
    // step 2: inv(post_rots) @ v (depth-independent)
    float a0 = dot3(iPR[0], v0, v1, v2);
    float a1 = dot3(iPR[1], v0, v1, v2);
    float a2 = dot3(iPR[2], v0, v1, v2);

    int   out_cls = IGN;
    float out_d   = 1.0f;

    for (int k = 0; k < NDEPTH; ++k) {
        float d  = __fadd_rn(1.0f, __fmul_rn(0.5f, (float)k));
        // step 3: lift by depth
        float b0 = __fmul_rn(a0, d);
        float b1 = __fmul_rn(a1, d);
        float b2 = __fmul_rn(a2, d);
        // step 4: inv(cam2img) @ b
        float c0 = dot3(iK[0], b0, b1, b2);
        float c1 = dot3(iK[1], b0, b1, b2);
        float c2 = dot3(iK[2], b0, b1, b2);
        // step 5: cam2ego rot + trans
        float e0 = __fadd_rn(dot3(R[0], c0, c1, c2), tx);
        float e1 = __fadd_rn(dot3(R[1], c0, c1, c2), ty);
        float e2 = __fadd_rn(dot3(R[2], c0, c1, c2), tz);
        // occ-cell units
        float eo0 = __fmul_rn(e0, 2.5f);
        float eo1 = __fmul_rn(e1, 2.5f);
        float eo2 = __fmul_rn(e2, 2.5f);
        // grid coords = ego_occ - xyz_min
        float g0 = __fsub_rn(eo0, -100.0f);
        float g1 = __fsub_rn(eo1, -100.0f);
        float g2 = __fsub_rn(eo2, -3.0f);
        // norm = g/(max-min)*2 - 1, inclusive bounds check
        float n0 = __fsub_rn(__fmul_rn(__fdiv_rn(g0, 200.0f), 2.0f), 1.0f);
        float n1 = __fsub_rn(__fmul_rn(__fdiv_rn(g1, 200.0f), 2.0f), 1.0f);
        float n2 = __fsub_rn(__fmul_rn(__fdiv_rn(g2, 16.0f),  2.0f), 1.0f);
        bool inb = (n0 >= -1.0f) && (n0 <= 1.0f) &&
                   (n1 >= -1.0f) && (n1 <= 1.0f) &&
                   (n2 >= -1.0f) && (n2 <= 1.0f);
        if (inb) {
            int ix = min(max((int)floorf(g0), 0), XDIM - 1);
            int iy = min(max((int)floorf(g1), 0), YDIM - 1);
            int iz = min(max((int)floorf(g2), 0), ZDIM - 1);
            const float* p = sem_map + (size_t)((ix * YDIM + iy) * ZDIM + iz) * NCLS;
            // argmax over 10 classes, first-max (softmax is monotone)
            float best = p[0];
            int   bi   = 0;
            #pragma unroll
            for (int c = 1; c < NCLS; ++c) {
                float vc = p[c];
                if (vc > best) { best = vc; bi = c; }
            }
            if (bi != IGN) { out_cls = bi; out_d = d; break; }
        }
    }

    int oi = (n * IMG_H + h) * IMG_W + w;
    out[oi] = (float)out_cls;        // sem_view (float32)
    out[NCAM * PPC + oi] = out_d;    // depth_map
}

extern "C" void kernel_launch(void* const* d_in, const int* in_sizes, int n_in,
                              void* d_out, int out_size, void* d_ws, size_t ws_size,
                              hipStream_t stream) {
    const float* c2e_rot    = (const float*)d_in[0];
    const float* c2e_trans  = (const float*)d_in[1];
    const float* cam2img    = (const float*)d_in[2];
    const float* post_rots  = (const float*)d_in[3];
    const float* post_trans = (const float*)d_in[4];
    // d_in[5] = bda (unused), d_in[7] = sem_view_map (unused), d_in[8] = occ_score (unused)
    const float* sem_map    = (const float*)d_in[6];
    float* out = (float*)d_out;

    const int total = NCAM * IMG_H * IMG_W;
    dim3 grid((total + 255) / 256), block(256);
    Pesudo_RenderNet_kernel<<<grid, block, 0, stream>>>(
        c2e_rot, c2e_trans, cam2img, post_rots, post_trans, sem_map, out);
}

// Round 3
// 17.163 us; speedup vs baseline: 2.1562x; 2.1562x over previous
//
#include <hip/hip_runtime.h>

// Pesudo_RenderNet — per-camera frustum raycast into a semantic voxel grid.
// Outputs (concat float32): sem_view (1,5,64,176), depth_map (1,5,64,176).
//
// Two kernels:
//  A) build uint8 argmax table over the 200x200x16 voxel grid (into d_ws)
//  B) raycast with 8 depth-parallel lanes per pixel + shfl min-reduce
//
// Numerics replicate numpy fp32 exactly (validated round 2, absmax 0.0):
//  - np.linalg.inv == LAPACK sgesv (getf2 partial pivot + getrs, reciprocal
//    diag multiplies)
//  - np.einsum (optimize=False) == sequential mul+add fp32, no FMA

#define IMG_H 64
#define IMG_W 176
#define NCAM  5
#define NDEPTH 88
#define XDIM 200
#define YDIM 200
#define ZDIM 16
#define NVOX (XDIM * YDIM * ZDIM)
#define NCLS 10
#define IGN  9
#define PPC  (IMG_H * IMG_W)
#define SENT 0x7FFFFFFF

__device__ __forceinline__ float dot3(const float r[3], float v0, float v1, float v2) {
    return __fadd_rn(__fadd_rn(__fmul_rn(r[0], v0), __fmul_rn(r[1], v1)),
                     __fmul_rn(r[2], v2));
}

// 3x3 inverse replicating LAPACK sgesv in fp32 (numpy np.linalg.inv path).
__device__ void inv3x3_gesv(const float* __restrict__ m, float out[3][3]) {
    float a[3][3];
    #pragma unroll
    for (int r = 0; r < 3; ++r)
        #pragma unroll
        for (int c = 0; c < 3; ++c)
            a[r][c] = m[r * 3 + c];

    int piv0, piv1;
    {   // getf2 col 0
        int p = 0; float mx = fabsf(a[0][0]);
        if (fabsf(a[1][0]) > mx) { mx = fabsf(a[1][0]); p = 1; }
        if (fabsf(a[2][0]) > mx) { p = 2; }
        piv0 = p;
        if (p != 0) {
            #pragma unroll
            for (int c = 0; c < 3; ++c) { float t = a[0][c]; a[0][c] = a[p][c]; a[p][c] = t; }
        }
        float r0 = __fdiv_rn(1.0f, a[0][0]);
        a[1][0] = __fmul_rn(a[1][0], r0);
        a[2][0] = __fmul_rn(a[2][0], r0);
        #pragma unroll
        for (int j = 1; j < 3; ++j) {
            float t = -a[0][j];
            a[1][j] = __fadd_rn(a[1][j], __fmul_rn(a[1][0], t));
            a[2][j] = __fadd_rn(a[2][j], __fmul_rn(a[2][0], t));
        }
    }
    {   // getf2 col 1
        int p = 1; float mx = fabsf(a[1][1]);
        if (fabsf(a[2][1]) > mx) { p = 2; }
        piv1 = p;
        if (p != 1) {
            #pragma unroll
            for (int c = 0; c < 3; ++c) { float t = a[1][c]; a[1][c] = a[2][c]; a[2][c] = t; }
        }
        float r1 = __fdiv_rn(1.0f, a[1][1]);
        a[2][1] = __fmul_rn(a[2][1], r1);
        a[2][2] = __fadd_rn(a[2][2], __fmul_rn(a[2][1], -a[1][2]));
    }

    float iu0 = __fdiv_rn(1.0f, a[0][0]);
    float iu1 = __fdiv_rn(1.0f, a[1][1]);
    float iu2 = __fdiv_rn(1.0f, a[2][2]);

    #pragma unroll
    for (int k = 0; k < 3; ++k) {
        float b[3] = {0.0f, 0.0f, 0.0f};
        b[k] = 1.0f;
        { float t = b[0]; b[0] = b[piv0]; b[piv0] = t; }
        { float t = b[1]; b[1] = b[piv1]; b[piv1] = t; }
        b[1] = __fsub_rn(b[1], __fmul_rn(b[0], a[1][0]));
        b[2] = __fsub_rn(b[2], __fmul_rn(b[0], a[2][0]));
        b[2] = __fsub_rn(b[2], __fmul_rn(b[1], a[2][1]));
        b[2] = __fmul_rn(b[2], iu2);
        b[1] = __fsub_rn(b[1], __fmul_rn(b[2], a[1][2]));
        b[0] = __fsub_rn(b[0], __fmul_rn(b[2], a[0][2]));
        b[1] = __fmul_rn(b[1], iu1);
        b[0] = __fsub_rn(b[0], __fmul_rn(b[1], a[0][1]));
        b[0] = __fmul_rn(b[0], iu0);
        out[0][k] = b[0];
        out[1][k] = b[1];
        out[2][k] = b[2];
    }
}

// ---- Kernel A: per-voxel argmax (first-max) over 10 classes -> uint8 table
__global__ __launch_bounds__(256)
void build_table_kernel(const float* __restrict__ sem_map,
                        unsigned char* __restrict__ table) {
    int v = blockIdx.x * 256 + threadIdx.x;
    if (v >= NVOX) return;
    const float* p = sem_map + (size_t)v * NCLS;
    float best = p[0];
    int   bi   = 0;
    #pragma unroll
    for (int c = 1; c < NCLS; ++c) {
        float vc = p[c];
        if (vc > best) { best = vc; bi = c; }
    }
    table[v] = (unsigned char)bi;
}

// ---- Kernel B: raycast, 8 depth-parallel lanes per pixel
__global__ __launch_bounds__(256)
void raycast_kernel(const float* __restrict__ c2e_rot,
                    const float* __restrict__ c2e_trans,
                    const float* __restrict__ cam2img,
                    const float* __restrict__ post_rots,
                    const float* __restrict__ post_trans,
                    const unsigned char* __restrict__ table,
                    float* __restrict__ out) {
    int tid = blockIdx.x * 256 + threadIdx.x;
    int g = tid >> 3;                 // pixel id (grid sized exactly)
    int l = tid & 7;                  // depth sub-lane 0..7
    int n   = g / PPC;
    int rem = g - n * PPC;
    int h   = rem / IMG_W;
    int w   = rem - h * IMG_W;

    float iPR[3][3], iK[3][3], R[3][3];
    inv3x3_gesv(post_rots + n * 9, iPR);
    inv3x3_gesv(cam2img  + n * 9, iK);
    #pragma unroll
    for (int i = 0; i < 3; ++i)
        #pragma unroll
        for (int j = 0; j < 3; ++j)
            R[i][j] = c2e_rot[n * 9 + i * 3 + j];
    float tx  = c2e_trans[n * 3 + 0], ty  = c2e_trans[n * 3 + 1], tz  = c2e_trans[n * 3 + 2];
    float tp0 = post_trans[n * 3 + 0], tp1 = post_trans[n * 3 + 1], tp2 = post_trans[n * 3 + 2];

    float x = (float)w + 0.5f;
    float y = (float)h + 0.5f;
    float v0 = __fsub_rn(__fmul_rn(4.0f, x), tp0);
    float v1 = __fsub_rn(__fmul_rn(4.0f, y), tp1);
    float v2 = __fsub_rn(1.0f, tp2);
    float a0 = dot3(iPR[0], v0, v1, v2);
    float a1 = dot3(iPR[1], v0, v1, v2);
    float a2 = dot3(iPR[2], v0, v1, v2);

    int code = SENT;   // (k<<8)|cls of first non-ignore in-bounds hit

    for (int j = 0; j < NDEPTH / 8; ++j) {
        int k = j * 8 + l;
        float d  = __fadd_rn(1.0f, __fmul_rn(0.5f, (float)k));
        float b0 = __fmul_rn(a0, d);
        float b1 = __fmul_rn(a1, d);
        float b2 = __fmul_rn(a2, d);
        float c0 = dot3(iK[0], b0, b1, b2);
        float c1 = dot3(iK[1], b0, b1, b2);
        float c2 = dot3(iK[2], b0, b1, b2);
        float e0 = __fadd_rn(dot3(R[0], c0, c1, c2), tx);
        float e1 = __fadd_rn(dot3(R[1], c0, c1, c2), ty);
        float e2 = __fadd_rn(dot3(R[2], c0, c1, c2), tz);
        float g0 = __fsub_rn(__fmul_rn(e0, 2.5f), -100.0f);
        float g1 = __fsub_rn(__fmul_rn(e1, 2.5f), -100.0f);
        float g2 = __fsub_rn(__fmul_rn(e2, 2.5f), -3.0f);
        float n0 = __fsub_rn(__fmul_rn(__fdiv_rn(g0, 200.0f), 2.0f), 1.0f);
        float n1 = __fsub_rn(__fmul_rn(__fdiv_rn(g1, 200.0f), 2.0f), 1.0f);
        float n2 = __fsub_rn(__fmul_rn(__fdiv_rn(g2, 16.0f),  2.0f), 1.0f);
        bool inb = (n0 >= -1.0f) && (n0 <= 1.0f) &&
                   (n1 >= -1.0f) && (n1 <= 1.0f) &&
                   (n2 >= -1.0f) && (n2 <= 1.0f);
        int my = SENT;
        if (inb) {
            int ix = min(max((int)floorf(g0), 0), XDIM - 1);
            int iy = min(max((int)floorf(g1), 0), YDIM - 1);
            int iz = min(max((int)floorf(g2), 0), ZDIM - 1);
            int cls = table[(ix * YDIM + iy) * ZDIM + iz];
            if (cls != IGN) my = (k << 8) | cls;
        }
        // min-reduce over the 8-lane group (k unique per lane -> first hit)
        my = min(my, __shfl_xor(my, 1, 8));
        my = min(my, __shfl_xor(my, 2, 8));
        my = min(my, __shfl_xor(my, 4, 8));
        if (my != SENT) { code = my; break; }
    }

    if (l == 0) {
        int oi = (n * IMG_H + h) * IMG_W + w;
        if (code != SENT) {
            int k = code >> 8;
            out[oi] = (float)(code & 255);
            out[NCAM * PPC + oi] = __fadd_rn(1.0f, __fmul_rn(0.5f, (float)k));
        } else {
            out[oi] = (float)IGN;
            out[NCAM * PPC + oi] = 1.0f;
        }
    }
}

extern "C" void kernel_launch(void* const* d_in, const int* in_sizes, int n_in,
                              void* d_out, int out_size, void* d_ws, size_t ws_size,
                              hipStream_t stream) {
    const float* c2e_rot    = (const float*)d_in[0];
    const float* c2e_trans  = (const float*)d_in[1];
    const float* cam2img    = (const float*)d_in[2];
    const float* post_rots  = (const float*)d_in[3];
    const float* post_trans = (const float*)d_in[4];
    // d_in[5]=bda, d_in[7]=sem_view_map, d_in[8]=occ_score : unused
    const float* sem_map    = (const float*)d_in[6];
    float* out = (float*)d_out;
    unsigned char* table = (unsigned char*)d_ws;   // NVOX = 640000 bytes

    // A: argmax table (640000 voxels)
    build_table_kernel<<<(NVOX + 255) / 256, 256, 0, stream>>>(sem_map, table);

    // B: raycast, 8 lanes per pixel; 56320 px * 8 / 256 = 1760 blocks exactly
    const int total_threads = NCAM * PPC * 8;
    raycast_kernel<<<total_threads / 256, 256, 0, stream>>>(
        c2e_rot, c2e_trans, cam2img, post_rots, post_trans, table, out);
}

// Round 4
// 12.747 us; speedup vs baseline: 2.9032x; 1.3464x over previous
//
#include <hip/hip_runtime.h>

// Pesudo_RenderNet — per-camera frustum raycast into a semantic voxel grid.
// Outputs (concat float32): sem_view (1,5,64,176), depth_map (1,5,64,176).
//
// Single kernel: 8 depth-parallel lanes per pixel, direct 10-float gather +
// inline argmax per probe (no precomputed table — the ray only touches ~10%
// of the voxel grid, so building the full table wastes a dispatch + 25.6 MB).
//
// Numerics replicate numpy fp32 exactly (validated rounds 2-3, absmax 0.0):
//  - np.linalg.inv == LAPACK sgesv (getf2 partial pivot + getrs, reciprocal
//    diag multiplies)
//  - np.einsum (optimize=False) == sequential mul+add fp32, no FMA

#define IMG_H 64
#define IMG_W 176
#define NCAM  5
#define NDEPTH 88
#define XDIM 200
#define YDIM 200
#define ZDIM 16
#define NCLS 10
#define IGN  9
#define PPC  (IMG_H * IMG_W)
#define SENT 0x7FFFFFFF

__device__ __forceinline__ float dot3(const float r[3], float v0, float v1, float v2) {
    return __fadd_rn(__fadd_rn(__fmul_rn(r[0], v0), __fmul_rn(r[1], v1)),
                     __fmul_rn(r[2], v2));
}

// 3x3 inverse replicating LAPACK sgesv in fp32 (numpy np.linalg.inv path).
__device__ void inv3x3_gesv(const float* __restrict__ m, float out[3][3]) {
    float a[3][3];
    #pragma unroll
    for (int r = 0; r < 3; ++r)
        #pragma unroll
        for (int c = 0; c < 3; ++c)
            a[r][c] = m[r * 3 + c];

    int piv0, piv1;
    {   // getf2 col 0
        int p = 0; float mx = fabsf(a[0][0]);
        if (fabsf(a[1][0]) > mx) { mx = fabsf(a[1][0]); p = 1; }
        if (fabsf(a[2][0]) > mx) { p = 2; }
        piv0 = p;
        if (p != 0) {
            #pragma unroll
            for (int c = 0; c < 3; ++c) { float t = a[0][c]; a[0][c] = a[p][c]; a[p][c] = t; }
        }
        float r0 = __fdiv_rn(1.0f, a[0][0]);
        a[1][0] = __fmul_rn(a[1][0], r0);
        a[2][0] = __fmul_rn(a[2][0], r0);
        #pragma unroll
        for (int j = 1; j < 3; ++j) {
            float t = -a[0][j];
            a[1][j] = __fadd_rn(a[1][j], __fmul_rn(a[1][0], t));
            a[2][j] = __fadd_rn(a[2][j], __fmul_rn(a[2][0], t));
        }
    }
    {   // getf2 col 1
        int p = 1; float mx = fabsf(a[1][1]);
        if (fabsf(a[2][1]) > mx) { p = 2; }
        piv1 = p;
        if (p != 1) {
            #pragma unroll
            for (int c = 0; c < 3; ++c) { float t = a[1][c]; a[1][c] = a[2][c]; a[2][c] = t; }
        }
        float r1 = __fdiv_rn(1.0f, a[1][1]);
        a[2][1] = __fmul_rn(a[2][1], r1);
        a[2][2] = __fadd_rn(a[2][2], __fmul_rn(a[2][1], -a[1][2]));
    }

    float iu0 = __fdiv_rn(1.0f, a[0][0]);
    float iu1 = __fdiv_rn(1.0f, a[1][1]);
    float iu2 = __fdiv_rn(1.0f, a[2][2]);

    #pragma unroll
    for (int k = 0; k < 3; ++k) {
        float b[3] = {0.0f, 0.0f, 0.0f};
        b[k] = 1.0f;
        { float t = b[0]; b[0] = b[piv0]; b[piv0] = t; }
        { float t = b[1]; b[1] = b[piv1]; b[piv1] = t; }
        b[1] = __fsub_rn(b[1], __fmul_rn(b[0], a[1][0]));
        b[2] = __fsub_rn(b[2], __fmul_rn(b[0], a[2][0]));
        b[2] = __fsub_rn(b[2], __fmul_rn(b[1], a[2][1]));
        b[2] = __fmul_rn(b[2], iu2);
        b[1] = __fsub_rn(b[1], __fmul_rn(b[2], a[1][2]));
        b[0] = __fsub_rn(b[0], __fmul_rn(b[2], a[0][2]));
        b[1] = __fmul_rn(b[1], iu1);
        b[0] = __fsub_rn(b[0], __fmul_rn(b[1], a[0][1]));
        b[0] = __fmul_rn(b[0], iu0);
        out[0][k] = b[0];
        out[1][k] = b[1];
        out[2][k] = b[2];
    }
}

__global__ __launch_bounds__(256)
void raycast_kernel(const float* __restrict__ c2e_rot,
                    const float* __restrict__ c2e_trans,
                    const float* __restrict__ cam2img,
                    const float* __restrict__ post_rots,
                    const float* __restrict__ post_trans,
                    const float* __restrict__ sem_map,
                    float* __restrict__ out) {
    int tid = blockIdx.x * 256 + threadIdx.x;
    int g = tid >> 3;                 // pixel id (grid sized exactly)
    int l = tid & 7;                  // depth sub-lane 0..7
    int n   = g / PPC;
    int rem = g - n * PPC;
    int h   = rem / IMG_W;
    int w   = rem - h * IMG_W;

    float iPR[3][3], iK[3][3], R[3][3];
    inv3x3_gesv(post_rots + n * 9, iPR);
    inv3x3_gesv(cam2img  + n * 9, iK);
    #pragma unroll
    for (int i = 0; i < 3; ++i)
        #pragma unroll
        for (int j = 0; j < 3; ++j)
            R[i][j] = c2e_rot[n * 9 + i * 3 + j];
    float tx  = c2e_trans[n * 3 + 0], ty  = c2e_trans[n * 3 + 1], tz  = c2e_trans[n * 3 + 2];
    float tp0 = post_trans[n * 3 + 0], tp1 = post_trans[n * 3 + 1], tp2 = post_trans[n * 3 + 2];

    float x = (float)w + 0.5f;
    float y = (float)h + 0.5f;
    float v0 = __fsub_rn(__fmul_rn(4.0f, x), tp0);
    float v1 = __fsub_rn(__fmul_rn(4.0f, y), tp1);
    float v2 = __fsub_rn(1.0f, tp2);
    float a0 = dot3(iPR[0], v0, v1, v2);
    float a1 = dot3(iPR[1], v0, v1, v2);
    float a2 = dot3(iPR[2], v0, v1, v2);

    int code = SENT;   // (k<<8)|cls of first non-ignore in-bounds hit

    for (int j = 0; j < NDEPTH / 8; ++j) {
        int k = j * 8 + l;
        float d  = __fadd_rn(1.0f, __fmul_rn(0.5f, (float)k));
        float b0 = __fmul_rn(a0, d);
        float b1 = __fmul_rn(a1, d);
        float b2 = __fmul_rn(a2, d);
        float c0 = dot3(iK[0], b0, b1, b2);
        float c1 = dot3(iK[1], b0, b1, b2);
        float c2 = dot3(iK[2], b0, b1, b2);
        float e0 = __fadd_rn(dot3(R[0], c0, c1, c2), tx);
        float e1 = __fadd_rn(dot3(R[1], c0, c1, c2), ty);
        float e2 = __fadd_rn(dot3(R[2], c0, c1, c2), tz);
        float g0 = __fsub_rn(__fmul_rn(e0, 2.5f), -100.0f);
        float g1 = __fsub_rn(__fmul_rn(e1, 2.5f), -100.0f);
        float g2 = __fsub_rn(__fmul_rn(e2, 2.5f), -3.0f);
        float n0 = __fsub_rn(__fmul_rn(__fdiv_rn(g0, 200.0f), 2.0f), 1.0f);
        float n1 = __fsub_rn(__fmul_rn(__fdiv_rn(g1, 200.0f), 2.0f), 1.0f);
        float n2 = __fsub_rn(__fmul_rn(__fdiv_rn(g2, 16.0f),  2.0f), 1.0f);
        bool inb = (n0 >= -1.0f) && (n0 <= 1.0f) &&
                   (n1 >= -1.0f) && (n1 <= 1.0f) &&
                   (n2 >= -1.0f) && (n2 <= 1.0f);
        int my = SENT;
        if (inb) {
            int ix = min(max((int)floorf(g0), 0), XDIM - 1);
            int iy = min(max((int)floorf(g1), 0), YDIM - 1);
            int iz = min(max((int)floorf(g2), 0), ZDIM - 1);
            // direct gather: 10 floats as 5 aligned float2 loads (byte offset
            // 40*v is 8B-aligned), all in flight together
            const float2* p2 = (const float2*)(sem_map + (size_t)((ix * YDIM + iy) * ZDIM + iz) * NCLS);
            float pv[NCLS];
            #pragma unroll
            for (int q = 0; q < 5; ++q) {
                float2 f = p2[q];
                pv[2 * q]     = f.x;
                pv[2 * q + 1] = f.y;
            }
            // argmax over 10 classes, first-max (softmax is monotone)
            float best = pv[0];
            int   bi   = 0;
            #pragma unroll
            for (int c = 1; c < NCLS; ++c) {
                if (pv[c] > best) { best = pv[c]; bi = c; }
            }
            if (bi != IGN) my = (k << 8) | bi;
        }
        // min-reduce over the 8-lane group (k unique per lane -> first hit)
        my = min(my, __shfl_xor(my, 1, 8));
        my = min(my, __shfl_xor(my, 2, 8));
        my = min(my, __shfl_xor(my, 4, 8));
        if (my != SENT) { code = my; break; }
    }

    if (l == 0) {
        int oi = (n * IMG_H + h) * IMG_W + w;
        if (code != SENT) {
            int k = code >> 8;
            out[oi] = (float)(code & 255);
            out[NCAM * PPC + oi] = __fadd_rn(1.0f, __fmul_rn(0.5f, (float)k));
        } else {
            out[oi] = (float)IGN;
            out[NCAM * PPC + oi] = 1.0f;
        }
    }
}

extern "C" void kernel_launch(void* const* d_in, const int* in_sizes, int n_in,
                              void* d_out, int out_size, void* d_ws, size_t ws_size,
                              hipStream_t stream) {
    const float* c2e_rot    = (const float*)d_in[0];
    const float* c2e_trans  = (const float*)d_in[1];
    const float* cam2img    = (const float*)d_in[2];
    const float* post_rots  = (const float*)d_in[3];
    const float* post_trans = (const float*)d_in[4];
    // d_in[5]=bda, d_in[7]=sem_view_map, d_in[8]=occ_score : unused
    const float* sem_map    = (const float*)d_in[6];
    float* out = (float*)d_out;

    // 56320 px * 8 lanes / 256 = 1760 blocks exactly
    const int total_threads = NCAM * PPC * 8;
    raycast_kernel<<<total_threads / 256, 256, 0, stream>>>(
        c2e_rot, c2e_trans, cam2img, post_rots, post_trans, sem_map, out);
}